// Round 1
// 506.488 us; speedup vs baseline: 1.6135x; 1.6135x over previous
//
#include <hip/hip_runtime.h>
#include <cstdint>
#include <cmath>

// ---------------------------------------------------------------------------
// RegionSelection on MI355X (gfx950) — R2: split-f16 MFMA GEMMs
//
//   K1: h1 = relu(W1 @ feat + b1)  via f16 hi/lo split (3 MFMA products)
//       h1 stored PRE-SPLIT as two u16 planes (hi, lo) for K2.
//   K2: h2 = relu(W2 @ h1 + b2)    same split GEMM, h1 already split.
//   K3: att = (sigmoid(w3 . h2 + b3) + cam) * 0.5      (unchanged)
//   K4: 3x argmax + 11x11 suppression                  (unchanged)
//   K5: crop 96 x 3 x 384 x 384                        (unchanged)
//
// Split math: x = hi + lo, hi = (f16)x (11 mantissa bits), lo = (f16)(x-hi).
// acc += hi_w*hi_f + hi_w*lo_f + lo_w*hi_f  (fp32 MFMA accum). Dropped
// lo*lo term <= 2^-22 relative: att abs err ~1e-5.
//
// GEMM structure: 128n x 128px block tile, K_STEP=32, 4 waves (2x2),
// wave tile 64x64 = 16 mfma_f32_16x16x32_f16 frags x 3 products.
// LDS tiles [128 rows][32 f16] with XOR swizzle (byte ^= (row&7)<<4):
// both b128 staging writes and fragment reads are even 8-accesses/bank.
// T14: next k-tile's global loads issued before the MFMA phase.
//
// Scratch in d_out regions area: h1hi u16 [0,32MB) h1lo [32,64MB)
// h2 f32 [64,96MB). All overwritten by K5 at the end.
// ---------------------------------------------------------------------------

typedef float f4 __attribute__((ext_vector_type(4)));
typedef _Float16 f16x8 __attribute__((ext_vector_type(8)));
typedef int i4 __attribute__((ext_vector_type(4)));

#define M_PIX 32768
#define COORDS_OFF 42467328      // 96*3*384*384 floats
#define ATT_OFF 42467712
#define H1LO_OFF 8388608         // float offset of h1lo plane (u16)
#define H2_OFF 16777216          // float offset of h2 (f32)

// LDS tile bases (in ints; each tile = 128 rows x 16 ints = 2048 ints = 8 KB)
#define WH_T 0
#define WL_T 2048
#define FH_T 4096
#define FL_T 6144

// swizzled int-index within a tile. row 0..127, k16 = f16 col (even).
// byte addr = (row*64 + 2*k16) ^ ((row&7)<<4): bijective, spreads the
// 64-row / fixed-k accesses over all 8 4-bank groups.
__device__ __forceinline__ int swz(int row, int k16) {
    return ((row << 4) + (k16 >> 1)) ^ ((row & 7) << 2);
}

// f32 -> packed f16 hi pair; lo pair via out-param.
__device__ __forceinline__ int split_pack(float v0, float v1, int& lop) {
    _Float16 h0 = (_Float16)v0, h1 = (_Float16)v1;
    float r0 = v0 - (float)h0, r1 = v1 - (float)h1;
    _Float16 l0 = (_Float16)r0, l1 = (_Float16)r1;
    unsigned int uh0 = __builtin_bit_cast(unsigned short, h0);
    unsigned int uh1 = __builtin_bit_cast(unsigned short, h1);
    unsigned int ul0 = __builtin_bit_cast(unsigned short, l0);
    unsigned int ul1 = __builtin_bit_cast(unsigned short, l1);
    lop = (int)(ul0 | (ul1 << 16));
    return (int)(uh0 | (uh1 << 16));
}

// ---------------------------------------------------------------------------
// MODE 0 (K1): F = fp32 global (features), outputs split u16 planes OA/OB.
// MODE 1 (K2): F = pre-split u16 planes FA/FB, outputs f32 OA.
// Block: 256 thr (4 waves), tile 128n x 128px, K_STEP = 32.
// ---------------------------------------------------------------------------
template<int MODE>
__global__ __launch_bounds__(256, 2) void gemm_mfma(
    const float* __restrict__ W, const void* __restrict__ FA,
    const void* __restrict__ FB, const float* __restrict__ bias,
    void* __restrict__ OA, void* __restrict__ OB,
    int Kdim, long fstride, int use_feat)
{
    __shared__ i4 ldsv[2048];                 // 32 KB
    int* lds = (int*)ldsv;

    const int t = threadIdx.x;
    const int lane = t & 63;
    const int wave = t >> 6;
    const int wn = wave >> 1, wp = wave & 1;  // 2x2 wave grid
    const int n0  = blockIdx.x * 128;
    const int px0 = blockIdx.y * 128;

    // staging: each thread owns one row (rl) and half the k-range (kb)
    const int rl = t & 127;
    const int kb = (t >> 7) * 16;

    const float* F32 = (const float*)FA;
    const unsigned short* FH16 = (const unsigned short*)FA;
    const unsigned short* FL16 = (const unsigned short*)FB;
    if constexpr (MODE == 0) {
        if (use_feat) F32 += ((size_t)(px0 >> 10) << 20) + (px0 & 1023) + rl;
        else          F32 += px0 + rl;
    } else {
        FH16 += px0 + rl;
        FL16 += px0 + rl;
    }
    const float* Wp = W + (size_t)(n0 + rl) * Kdim + kb;

    f4 acc[4][4];
    #pragma unroll
    for (int i = 0; i < 4; ++i)
        #pragma unroll
        for (int j = 0; j < 4; ++j) acc[i][j] = (f4){0.f, 0.f, 0.f, 0.f};

    float fv[16];
    unsigned short hv[16], lv[16];
    f4 wv[4];

    auto LOADS = [&](int k0) {
        if constexpr (MODE == 0) {
            #pragma unroll
            for (int j = 0; j < 16; ++j)
                fv[j] = F32[(size_t)(k0 + kb + j) * fstride];
        } else {
            #pragma unroll
            for (int j = 0; j < 16; ++j) {
                hv[j] = FH16[(size_t)(k0 + kb + j) * fstride];
                lv[j] = FL16[(size_t)(k0 + kb + j) * fstride];
            }
        }
        #pragma unroll
        for (int g = 0; g < 4; ++g)
            wv[g] = *(const f4*)(Wp + k0 + 4 * g);
    };

    auto STAGE = [&]() {
        // W: split-convert 16 floats -> 2x (b128 hi + b128 lo)
        #pragma unroll
        for (int g = 0; g < 2; ++g) {
            i4 hp, lp;
            #pragma unroll
            for (int j = 0; j < 4; ++j) {
                const int e = 8 * g + 2 * j;
                int lo;
                hp[j] = split_pack(wv[e >> 2][e & 3], wv[(e + 1) >> 2][(e + 1) & 3], lo);
                lp[j] = lo;
            }
            *(i4*)&lds[WH_T + swz(rl, kb + 8 * g)] = hp;
            *(i4*)&lds[WL_T + swz(rl, kb + 8 * g)] = lp;
        }
        // F
        #pragma unroll
        for (int g = 0; g < 2; ++g) {
            i4 hp, lp;
            if constexpr (MODE == 0) {
                #pragma unroll
                for (int j = 0; j < 4; ++j) {
                    int lo;
                    hp[j] = split_pack(fv[8 * g + 2 * j], fv[8 * g + 2 * j + 1], lo);
                    lp[j] = lo;
                }
            } else {
                #pragma unroll
                for (int j = 0; j < 4; ++j) {
                    hp[j] = (int)((unsigned int)hv[8 * g + 2 * j] |
                                  ((unsigned int)hv[8 * g + 2 * j + 1] << 16));
                    lp[j] = (int)((unsigned int)lv[8 * g + 2 * j] |
                                  ((unsigned int)lv[8 * g + 2 * j + 1] << 16));
                }
            }
            *(i4*)&lds[FH_T + swz(rl, kb + 8 * g)] = hp;
            *(i4*)&lds[FL_T + swz(rl, kb + 8 * g)] = lp;
        }
    };

    // fragment read coordinates: row = base + (lane&15), k = 8*(lane>>4)
    const int rA0 = 64 * wn + (lane & 15);
    const int rB0 = 64 * wp + (lane & 15);
    const int kg  = (lane >> 4) * 8;

    LOADS(0);
    for (int k0 = 0; k0 < Kdim; k0 += 32) {
        STAGE();
        if (k0 + 32 < Kdim) LOADS(k0 + 32);   // T14: in flight during MFMA
        __syncthreads();

        f16x8 bh[4], bl[4];
        #pragma unroll
        for (int nf = 0; nf < 4; ++nf) {
            bh[nf] = *(const f16x8*)&lds[FH_T + swz(rB0 + 16 * nf, kg)];
            bl[nf] = *(const f16x8*)&lds[FL_T + swz(rB0 + 16 * nf, kg)];
        }
        #pragma unroll
        for (int m = 0; m < 4; ++m) {
            f16x8 ah = *(const f16x8*)&lds[WH_T + swz(rA0 + 16 * m, kg)];
            f16x8 al = *(const f16x8*)&lds[WL_T + swz(rA0 + 16 * m, kg)];
            #pragma unroll
            for (int nf = 0; nf < 4; ++nf) {
                acc[m][nf] = __builtin_amdgcn_mfma_f32_16x16x32_f16(ah, bh[nf], acc[m][nf], 0, 0, 0);
                acc[m][nf] = __builtin_amdgcn_mfma_f32_16x16x32_f16(ah, bl[nf], acc[m][nf], 0, 0, 0);
                acc[m][nf] = __builtin_amdgcn_mfma_f32_16x16x32_f16(al, bh[nf], acc[m][nf], 0, 0, 0);
            }
        }
        __syncthreads();
    }

    // epilogue. C/D layout (verified): col = lane&15, row = (lane>>4)*4 + reg
    const int pxE = px0 + 64 * wp + (lane & 15);
    const int nE  = n0 + 64 * wn + 4 * (lane >> 4);
    unsigned short* o16a = (unsigned short*)OA;
    unsigned short* o16b = (unsigned short*)OB;
    float* o32 = (float*)OA;
    #pragma unroll
    for (int m = 0; m < 4; ++m) {
        const int n_m = nE + 16 * m;
        const f4 bv = *(const f4*)&bias[n_m];
        #pragma unroll
        for (int nf = 0; nf < 4; ++nf) {
            const int p = pxE + 16 * nf;
            #pragma unroll
            for (int r = 0; r < 4; ++r) {
                float v = fmaxf(acc[m][nf][r] + bv[r], 0.0f);
                if constexpr (MODE == 0) {
                    _Float16 h = (_Float16)v;
                    _Float16 l = (_Float16)(v - (float)h);
                    o16a[(size_t)(n_m + r) * M_PIX + p] = __builtin_bit_cast(unsigned short, h);
                    o16b[(size_t)(n_m + r) * M_PIX + p] = __builtin_bit_cast(unsigned short, l);
                } else {
                    o32[(size_t)(n_m + r) * M_PIX + p] = v;
                }
            }
        }
    }
}

// ---------------------------------------------------------------------------
// K3: att[p] = (sigmoid(b3 + sum_k w3[k]*h2[k][p]) + cam[p]) * 0.5
// ---------------------------------------------------------------------------
__global__ __launch_bounds__(256) void layer3_att(
    const float* __restrict__ h2, const float* __restrict__ w3,
    const float* __restrict__ b3, const float* __restrict__ cam,
    float* __restrict__ att)
{
    const int p = blockIdx.x * 256 + threadIdx.x;
    float s = b3[0];
    #pragma unroll 8
    for (int k = 0; k < 256; ++k)
        s = fmaf(w3[k], h2[(size_t)k * M_PIX + p], s);
    const float sg = 1.0f / (1.0f + expf(-s));
    att[p] = (sg + cam[p]) * 0.5f;
}

// ---------------------------------------------------------------------------
// K4: per-batch 3x (argmax + suppression). 1 wave per batch.
// ---------------------------------------------------------------------------
__global__ __launch_bounds__(64) void peaks_kernel(
    const float* __restrict__ att, float* __restrict__ coords,
    int* __restrict__ wsyx)
{
    const int b = blockIdx.x;
    const int lane = threadIdx.x;
    __shared__ float s[1024];
    for (int i = lane; i < 1024; i += 64) s[i] = att[b * 1024 + i];
    __syncthreads();

    for (int kpk = 0; kpk < 3; ++kpk) {
        float bv = -1.0f;
        int bi = 0x7fffffff;
        for (int i = lane; i < 1024; i += 64) {
            float v = s[i];
            if (v > bv) { bv = v; bi = i; }
        }
        for (int off = 32; off >= 1; off >>= 1) {
            float ov = __shfl_down(bv, off);
            int   oi = __shfl_down(bi, off);
            if (ov > bv || (ov == bv && oi < bi)) { bv = ov; bi = oi; }
        }
        bv = __shfl(bv, 0);
        bi = __shfl(bi, 0);

        int fy, fx;
        if (bv > 0.0f) { fy = bi >> 5; fx = bi & 31; }
        else           { fy = 16;      fx = 16; }

        for (int i = lane; i < 1024; i += 64) {
            const int y = i >> 5, x = i & 31;
            const int dy = y > fy ? y - fy : fy - y;
            const int dx = x > fx ? x - fx : fx - x;
            if (dy <= 5 && dx <= 5) s[i] = 0.0f;
        }
        __syncthreads();

        if (lane == 0) {
            int y1 = fy * 16 - 192; y1 = y1 < 0 ? 0 : (y1 > 128 ? 128 : y1);
            int x1 = fx * 16 - 192; x1 = x1 < 0 ? 0 : (x1 > 128 ? 128 : x1);
            const int idx = b * 3 + kpk;
            coords[idx * 4 + 0] = (float)x1;
            coords[idx * 4 + 1] = (float)y1;
            coords[idx * 4 + 2] = (float)(x1 + 384);
            coords[idx * 4 + 3] = (float)(y1 + 384);
            wsyx[idx * 2 + 0] = y1;
            wsyx[idx * 2 + 1] = x1;
        }
        __syncthreads();
    }
}

// ---------------------------------------------------------------------------
// K5: crop 96 regions x 3ch x 384x384 (x1 is 16-float aligned).
// ---------------------------------------------------------------------------
__global__ __launch_bounds__(256) void crop_kernel(
    const float* __restrict__ orig, const int* __restrict__ wsyx,
    float* __restrict__ out)
{
    const int id = blockIdx.x * 256 + threadIdx.x;
    const int r    = id / (3 * 384 * 96);
    const int rem  = id - r * (3 * 384 * 96);
    const int c    = rem / (384 * 96);
    const int rem2 = rem - c * (384 * 96);
    const int row  = rem2 / 96;
    const int col  = (rem2 - row * 96) * 4;
    const int b = r / 3;
    const int y1 = wsyx[r * 2], x1 = wsyx[r * 2 + 1];
    const float* src = orig + (size_t)b * 786432 + (size_t)c * 262144
                     + (size_t)(y1 + row) * 512 + x1 + col;
    *(f4*)(out + (size_t)id * 4) = *(const f4*)src;
}

// ---------------------------------------------------------------------------
extern "C" void kernel_launch(void* const* d_in, const int* in_sizes, int n_in,
                              void* d_out, int out_size, void* d_ws, size_t ws_size,
                              hipStream_t stream)
{
    const float* features = (const float*)d_in[0];  // [32,1024,32,32]
    const float* cam      = (const float*)d_in[1];  // [32,32,32]
    const float* original = (const float*)d_in[2];  // [32,3,512,512]
    const float* w1 = (const float*)d_in[3];        // [512,1024]
    const float* b1 = (const float*)d_in[4];
    const float* w2 = (const float*)d_in[5];        // [256,512]
    const float* b2 = (const float*)d_in[6];
    const float* w3 = (const float*)d_in[7];        // [1,256]
    const float* b3 = (const float*)d_in[8];

    float* out    = (float*)d_out;
    unsigned short* h1hi = (unsigned short*)out;             // 32 MB scratch
    unsigned short* h1lo = (unsigned short*)(out + H1LO_OFF);// 32 MB scratch
    float* h2     = out + H2_OFF;                            // 32 MB scratch
    float* att    = out + ATT_OFF;
    float* coords = out + COORDS_OFF;
    int*   wsyx   = (int*)d_ws;

    dim3 b256(256);
    // K1: 512 x 32768, K=1024, split-f16 MFMA, outputs pre-split h1
    gemm_mfma<0><<<dim3(4, 256), b256, 0, stream>>>(
        w1, features, nullptr, b1, h1hi, h1lo, 1024, 1024L, 1);
    // K2: 256 x 32768, K=512, consumes pre-split h1, outputs f32 h2
    gemm_mfma<1><<<dim3(2, 256), b256, 0, stream>>>(
        w2, h1hi, h1lo, b2, h2, nullptr, 512, (long)M_PIX, 0);
    // K3
    layer3_att<<<dim3(128), b256, 0, stream>>>(h2, w3, b3, cam, att);
    // K4
    peaks_kernel<<<dim3(32), dim3(64), 0, stream>>>(att, coords, wsyx);
    // K5
    crop_kernel<<<dim3(41472), b256, 0, stream>>>(original, wsyx, out);
}

// Round 2
// 479.620 us; speedup vs baseline: 1.7039x; 1.0560x over previous
//
#include <hip/hip_runtime.h>
#include <cstdint>
#include <cmath>

// ---------------------------------------------------------------------------
// RegionSelection on MI355X (gfx950) — R3: split-f16 MFMA GEMMs, staged via
// global_load_lds with pre-split weights.
//
//   P0: split W1, W2 into u16 hi/lo planes (one-time, ~5us)
//   K1: h1 = relu(W1 @ feat + b1)  W via global_load_lds (pre-split planes,
//       double-buffered); F split on the fly (only 4x redundancy).
//       h1 stored PRE-SPLIT (hi/lo u16 planes).
//   K2: h2 = relu(W2 @ h1 + b2)    W via global_load_lds; F from pre-split
//       h1 planes (pack only, no split math).
//   K3/K4/K5 unchanged.
//
// Fixes vs R2:
//  - T14 actually works now: next-tile W DMA + F loads issued AFTER the
//    stage barrier, so the compiler's vmcnt(0)-before-barrier drain lands
//    at the END of the MFMA phase, not before it.
//  - W staging has zero VALU and zero ds_write (global_load_lds, 16B),
//    with inverse-swizzled per-lane global source (rule #21).
//  - XCD block remap: the NB n-blocks sharing one px-tile get the same
//    (blockid % 8) -> same XCD L2 -> F-tile fetched once per XCD.
//
// Numerics identical to R2 (same split, same MFMA order): absmax 0.001953125.
//
// Scratch in d_out (floats):
//   h1hi [0, 8388608)  h1lo [8388608, 16777216)  h2 [16777216, 25165824)
//   w1hi [25165824, 25427968) w1lo [25427968, 25690112)
//   w2hi [25690112, 25755648) w2lo [25755648, 25821184)
// All < 42467328 (regions area), overwritten by K5 at the end.
// ---------------------------------------------------------------------------

typedef float f4 __attribute__((ext_vector_type(4)));
typedef _Float16 f16x8 __attribute__((ext_vector_type(8)));
typedef int i4 __attribute__((ext_vector_type(4)));
typedef unsigned short u16x4 __attribute__((ext_vector_type(4)));

#define M_PIX 32768
#define COORDS_OFF 42467328
#define ATT_OFF 42467712
#define H1LO_OFF 8388608
#define H2_OFF 16777216
#define W1HI_OFF 25165824
#define W1LO_OFF 25427968
#define W2HI_OFF 25690112
#define W2LO_OFF 25755648

// LDS int-index tile bases. W double-buffered: buf*4096 (+0 hi, +2048 lo).
// F tiles fixed: FH 8192, FL 10240. Total 12288 ints = 48 KB.
#define FH_T 8192
#define FL_T 10240

#define GLOAD16(gp, lp) \
    __builtin_amdgcn_global_load_lds( \
        (const __attribute__((address_space(1))) unsigned int*)(gp), \
        (__attribute__((address_space(3))) unsigned int*)(lp), 16, 0, 0)

// swizzled int-index within an 8KB tile (128 rows x 16 ints).
// idx = (row*16 + k16/2) ^ ((row&7)<<2). XOR bit4 pair-swaps rows r<->r^1
// for (r&4); bijective, spreads fixed-column reads over all 8 16B groups.
__device__ __forceinline__ int swz(int row, int k16) {
    return ((row << 4) + (k16 >> 1)) ^ ((row & 7) << 2);
}

__device__ __forceinline__ int split_pack(float v0, float v1, int& lop) {
    _Float16 h0 = (_Float16)v0, h1 = (_Float16)v1;
    float r0 = v0 - (float)h0, r1 = v1 - (float)h1;
    _Float16 l0 = (_Float16)r0, l1 = (_Float16)r1;
    unsigned int uh0 = __builtin_bit_cast(unsigned short, h0);
    unsigned int uh1 = __builtin_bit_cast(unsigned short, h1);
    unsigned int ul0 = __builtin_bit_cast(unsigned short, l0);
    unsigned int ul1 = __builtin_bit_cast(unsigned short, l1);
    lop = (int)(ul0 | (ul1 << 16));
    return (int)(uh0 | (uh1 << 16));
}

// ---------------------------------------------------------------------------
// P0: split a fp32 array into u16 hi/lo planes. n4 = count/4.
// ---------------------------------------------------------------------------
__global__ __launch_bounds__(256) void split_plane(
    const float* __restrict__ src, unsigned short* __restrict__ hi,
    unsigned short* __restrict__ lo, int n4)
{
    const int i = blockIdx.x * 256 + threadIdx.x;
    if (i >= n4) return;
    f4 v = *(const f4*)(src + 4 * (size_t)i);
    u16x4 hv, lv;
    #pragma unroll
    for (int j = 0; j < 4; ++j) {
        _Float16 h = (_Float16)v[j];
        _Float16 l = (_Float16)(v[j] - (float)h);
        hv[j] = __builtin_bit_cast(unsigned short, h);
        lv[j] = __builtin_bit_cast(unsigned short, l);
    }
    *(u16x4*)(hi + 4 * (size_t)i) = hv;
    *(u16x4*)(lo + 4 * (size_t)i) = lv;
}

// ---------------------------------------------------------------------------
// MODE 0 (K1): F = fp32 global (features); outputs split u16 planes OA/OB.
// MODE 1 (K2): F = pre-split u16 planes FA/FB; outputs f32 OA.
// W always from pre-split u16 planes via global_load_lds, double-buffered.
// Block: 256 thr (4 waves), tile 128n x 128px, K_STEP = 32, grid 1-D remapped.
// ---------------------------------------------------------------------------
template<int MODE, int NBL>
__global__ __launch_bounds__(256, 2) void gemm_mfma(
    const unsigned short* __restrict__ WH, const unsigned short* __restrict__ WL,
    const void* __restrict__ FA, const void* __restrict__ FB,
    const float* __restrict__ bias, void* __restrict__ OA, void* __restrict__ OB,
    int Kdim, long fstride, int use_feat)
{
    __shared__ i4 ldsv[3072];                 // 48 KB
    int* lds = (int*)ldsv;

    const int t = threadIdx.x;
    const int lane = t & 63;
    const int wave = t >> 6;
    const int wn = wave >> 1, wp = wave & 1;

    // XCD remap: the (1<<NBL) n-blocks of one px-tile share blockid%8 -> XCD
    const int f = blockIdx.x;
    const int nb = (f >> 3) & ((1 << NBL) - 1);
    const int pb = (f & 7) | ((f >> (3 + NBL)) << 3);
    const int n0  = nb * 128;
    const int px0 = pb * 128;

    // staging ownership (F tiles): row rl, k-half kb
    const int rl = t & 127;
    const int kb = (t >> 7) * 16;

    const float* F32 = (const float*)FA;
    const unsigned short* FH16 = (const unsigned short*)FA;
    const unsigned short* FL16 = (const unsigned short*)FB;
    if constexpr (MODE == 0) {
        if (use_feat) F32 += ((size_t)(px0 >> 10) << 20) + (px0 & 1023) + rl;
        else          F32 += px0 + rl;
    } else {
        FH16 += px0 + rl;
        FL16 += px0 + rl;
    }

    // W global_load_lds source pre-swizzle: instruction i covers LDS ints
    // [256i, 256i+256); lane l owns ints L=256i+4l..+3. Invert swz:
    //   rL = L>>4; r = (rL&4) ? rL^1 : rL; c = (L&15) ^ ((r&3)<<2)
    // -> lane loads plane[(n0+r)*Kdim + k0 + 2c .. +8).
    int wg_off[2];
    #pragma unroll
    for (int j = 0; j < 2; ++j) {
        const int i  = 2 * wave + j;
        const int rL = 16 * i + (lane >> 2);
        const int r  = (rL & 4) ? (rL ^ 1) : rL;
        const int c  = (4 * (lane & 3)) ^ ((r & 3) << 2);
        wg_off[j] = (n0 + r) * Kdim + 2 * c;
    }

    f4 acc[4][4];
    #pragma unroll
    for (int i = 0; i < 4; ++i)
        #pragma unroll
        for (int j = 0; j < 4; ++j) acc[i][j] = (f4){0.f, 0.f, 0.f, 0.f};

    float fv[16];
    unsigned short hv[16], lv[16];

    auto W_GLOADS = [&](int buf, int k0) {
        const int wb = buf * 4096;
        #pragma unroll
        for (int j = 0; j < 2; ++j) {
            const int i = 2 * wave + j;
            GLOAD16(WH + wg_off[j] + k0, &lds[wb + 256 * i]);
            GLOAD16(WL + wg_off[j] + k0, &lds[wb + 2048 + 256 * i]);
        }
    };

    auto LOADS_F = [&](int k0) {
        if constexpr (MODE == 0) {
            #pragma unroll
            for (int j = 0; j < 16; ++j)
                fv[j] = F32[(size_t)(k0 + kb + j) * fstride];
        } else {
            #pragma unroll
            for (int j = 0; j < 16; ++j) {
                hv[j] = FH16[(size_t)(k0 + kb + j) * fstride];
                lv[j] = FL16[(size_t)(k0 + kb + j) * fstride];
            }
        }
    };

    auto STAGE_F = [&]() {
        #pragma unroll
        for (int g = 0; g < 2; ++g) {
            i4 hp, lp;
            if constexpr (MODE == 0) {
                #pragma unroll
                for (int j = 0; j < 4; ++j) {
                    int lo;
                    hp[j] = split_pack(fv[8 * g + 2 * j], fv[8 * g + 2 * j + 1], lo);
                    lp[j] = lo;
                }
            } else {
                #pragma unroll
                for (int j = 0; j < 4; ++j) {
                    hp[j] = (int)((unsigned int)hv[8 * g + 2 * j] |
                                  ((unsigned int)hv[8 * g + 2 * j + 1] << 16));
                    lp[j] = (int)((unsigned int)lv[8 * g + 2 * j] |
                                  ((unsigned int)lv[8 * g + 2 * j + 1] << 16));
                }
            }
            *(i4*)&lds[FH_T + swz(rl, kb + 8 * g)] = hp;
            *(i4*)&lds[FL_T + swz(rl, kb + 8 * g)] = lp;
        }
    };

    const int rA0 = 64 * wn + (lane & 15);
    const int rB0 = 64 * wp + (lane & 15);
    const int kg  = (lane >> 4) * 8;

    W_GLOADS(0, 0);
    LOADS_F(0);
    int cur = 0;
    for (int k0 = 0; k0 < Kdim; k0 += 32) {
        STAGE_F();
        __syncthreads();   // drains W DMA (cur) + F ds_writes; no global loads pending

        // T14: next tile's W DMA + F loads in flight across the MFMA phase
        if (k0 + 32 < Kdim) { W_GLOADS(cur ^ 1, k0 + 32); LOADS_F(k0 + 32); }

        const int wb = cur * 4096;
        f16x8 bh[4], bl[4];
        #pragma unroll
        for (int nf = 0; nf < 4; ++nf) {
            bh[nf] = *(const f16x8*)&lds[FH_T + swz(rB0 + 16 * nf, kg)];
            bl[nf] = *(const f16x8*)&lds[FL_T + swz(rB0 + 16 * nf, kg)];
        }
        #pragma unroll
        for (int m = 0; m < 4; ++m) {
            f16x8 ah = *(const f16x8*)&lds[wb + swz(rA0 + 16 * m, kg)];
            f16x8 al = *(const f16x8*)&lds[wb + 2048 + swz(rA0 + 16 * m, kg)];
            #pragma unroll
            for (int nf = 0; nf < 4; ++nf) {
                acc[m][nf] = __builtin_amdgcn_mfma_f32_16x16x32_f16(ah, bh[nf], acc[m][nf], 0, 0, 0);
                acc[m][nf] = __builtin_amdgcn_mfma_f32_16x16x32_f16(ah, bl[nf], acc[m][nf], 0, 0, 0);
                acc[m][nf] = __builtin_amdgcn_mfma_f32_16x16x32_f16(al, bh[nf], acc[m][nf], 0, 0, 0);
            }
        }
        __syncthreads();   // drains the prefetches (they had the MFMA phase)
        cur ^= 1;
    }

    // epilogue. C/D layout: col = lane&15, row = (lane>>4)*4 + reg
    const int pxE = px0 + 64 * wp + (lane & 15);
    const int nE  = n0 + 64 * wn + 4 * (lane >> 4);
    unsigned short* o16a = (unsigned short*)OA;
    unsigned short* o16b = (unsigned short*)OB;
    float* o32 = (float*)OA;
    #pragma unroll
    for (int m = 0; m < 4; ++m) {
        const int n_m = nE + 16 * m;
        const f4 bv = *(const f4*)&bias[n_m];
        #pragma unroll
        for (int nf = 0; nf < 4; ++nf) {
            const int p = pxE + 16 * nf;
            #pragma unroll
            for (int r = 0; r < 4; ++r) {
                float v = fmaxf(acc[m][nf][r] + bv[r], 0.0f);
                if constexpr (MODE == 0) {
                    _Float16 h = (_Float16)v;
                    _Float16 l = (_Float16)(v - (float)h);
                    o16a[(size_t)(n_m + r) * M_PIX + p] = __builtin_bit_cast(unsigned short, h);
                    o16b[(size_t)(n_m + r) * M_PIX + p] = __builtin_bit_cast(unsigned short, l);
                } else {
                    o32[(size_t)(n_m + r) * M_PIX + p] = v;
                }
            }
        }
    }
}

// ---------------------------------------------------------------------------
// K3: att[p] = (sigmoid(b3 + sum_k w3[k]*h2[k][p]) + cam[p]) * 0.5
// ---------------------------------------------------------------------------
__global__ __launch_bounds__(256) void layer3_att(
    const float* __restrict__ h2, const float* __restrict__ w3,
    const float* __restrict__ b3, const float* __restrict__ cam,
    float* __restrict__ att)
{
    const int p = blockIdx.x * 256 + threadIdx.x;
    float s = b3[0];
    #pragma unroll 8
    for (int k = 0; k < 256; ++k)
        s = fmaf(w3[k], h2[(size_t)k * M_PIX + p], s);
    const float sg = 1.0f / (1.0f + expf(-s));
    att[p] = (sg + cam[p]) * 0.5f;
}

// ---------------------------------------------------------------------------
// K4: per-batch 3x (argmax + suppression). 1 wave per batch.
// ---------------------------------------------------------------------------
__global__ __launch_bounds__(64) void peaks_kernel(
    const float* __restrict__ att, float* __restrict__ coords,
    int* __restrict__ wsyx)
{
    const int b = blockIdx.x;
    const int lane = threadIdx.x;
    __shared__ float s[1024];
    for (int i = lane; i < 1024; i += 64) s[i] = att[b * 1024 + i];
    __syncthreads();

    for (int kpk = 0; kpk < 3; ++kpk) {
        float bv = -1.0f;
        int bi = 0x7fffffff;
        for (int i = lane; i < 1024; i += 64) {
            float v = s[i];
            if (v > bv) { bv = v; bi = i; }
        }
        for (int off = 32; off >= 1; off >>= 1) {
            float ov = __shfl_down(bv, off);
            int   oi = __shfl_down(bi, off);
            if (ov > bv || (ov == bv && oi < bi)) { bv = ov; bi = oi; }
        }
        bv = __shfl(bv, 0);
        bi = __shfl(bi, 0);

        int fy, fx;
        if (bv > 0.0f) { fy = bi >> 5; fx = bi & 31; }
        else           { fy = 16;      fx = 16; }

        for (int i = lane; i < 1024; i += 64) {
            const int y = i >> 5, x = i & 31;
            const int dy = y > fy ? y - fy : fy - y;
            const int dx = x > fx ? x - fx : fx - x;
            if (dy <= 5 && dx <= 5) s[i] = 0.0f;
        }
        __syncthreads();

        if (lane == 0) {
            int y1 = fy * 16 - 192; y1 = y1 < 0 ? 0 : (y1 > 128 ? 128 : y1);
            int x1 = fx * 16 - 192; x1 = x1 < 0 ? 0 : (x1 > 128 ? 128 : x1);
            const int idx = b * 3 + kpk;
            coords[idx * 4 + 0] = (float)x1;
            coords[idx * 4 + 1] = (float)y1;
            coords[idx * 4 + 2] = (float)(x1 + 384);
            coords[idx * 4 + 3] = (float)(y1 + 384);
            wsyx[idx * 2 + 0] = y1;
            wsyx[idx * 2 + 1] = x1;
        }
        __syncthreads();
    }
}

// ---------------------------------------------------------------------------
// K5: crop 96 regions x 3ch x 384x384 (x1 is 16-float aligned).
// ---------------------------------------------------------------------------
__global__ __launch_bounds__(256) void crop_kernel(
    const float* __restrict__ orig, const int* __restrict__ wsyx,
    float* __restrict__ out)
{
    const int id = blockIdx.x * 256 + threadIdx.x;
    const int r    = id / (3 * 384 * 96);
    const int rem  = id - r * (3 * 384 * 96);
    const int c    = rem / (384 * 96);
    const int rem2 = rem - c * (384 * 96);
    const int row  = rem2 / 96;
    const int col  = (rem2 - row * 96) * 4;
    const int b = r / 3;
    const int y1 = wsyx[r * 2], x1 = wsyx[r * 2 + 1];
    const float* src = orig + (size_t)b * 786432 + (size_t)c * 262144
                     + (size_t)(y1 + row) * 512 + x1 + col;
    *(f4*)(out + (size_t)id * 4) = *(const f4*)src;
}

// ---------------------------------------------------------------------------
extern "C" void kernel_launch(void* const* d_in, const int* in_sizes, int n_in,
                              void* d_out, int out_size, void* d_ws, size_t ws_size,
                              hipStream_t stream)
{
    const float* features = (const float*)d_in[0];  // [32,1024,32,32]
    const float* cam      = (const float*)d_in[1];  // [32,32,32]
    const float* original = (const float*)d_in[2];  // [32,3,512,512]
    const float* w1 = (const float*)d_in[3];        // [512,1024]
    const float* b1 = (const float*)d_in[4];
    const float* w2 = (const float*)d_in[5];        // [256,512]
    const float* b2 = (const float*)d_in[6];
    const float* w3 = (const float*)d_in[7];        // [1,256]
    const float* b3 = (const float*)d_in[8];

    float* out    = (float*)d_out;
    unsigned short* h1hi = (unsigned short*)out;
    unsigned short* h1lo = (unsigned short*)(out + H1LO_OFF);
    float* h2     = out + H2_OFF;
    unsigned short* w1hi = (unsigned short*)(out + W1HI_OFF);
    unsigned short* w1lo = (unsigned short*)(out + W1LO_OFF);
    unsigned short* w2hi = (unsigned short*)(out + W2HI_OFF);
    unsigned short* w2lo = (unsigned short*)(out + W2LO_OFF);
    float* att    = out + ATT_OFF;
    float* coords = out + COORDS_OFF;
    int*   wsyx   = (int*)d_ws;

    dim3 b256(256);
    // P0: pre-split weights (bit-identical to in-loop split)
    split_plane<<<dim3(512), b256, 0, stream>>>(w1, w1hi, w1lo, 131072);
    split_plane<<<dim3(128), b256, 0, stream>>>(w2, w2hi, w2lo, 32768);
    // K1: 512 x 32768, K=1024
    gemm_mfma<0, 2><<<dim3(1024), b256, 0, stream>>>(
        w1hi, w1lo, features, nullptr, b1, h1hi, h1lo, 1024, 1024L, 1);
    // K2: 256 x 32768, K=512
    gemm_mfma<1, 1><<<dim3(512), b256, 0, stream>>>(
        w2hi, w2lo, h1hi, h1lo, b2, h2, nullptr, 512, (long)M_PIX, 0);
    // K3
    layer3_att<<<dim3(128), b256, 0, stream>>>(h2, w3, b3, cam, att);
    // K4
    peaks_kernel<<<dim3(32), dim3(64), 0, stream>>>(att, coords, wsyx);
    // K5
    crop_kernel<<<dim3(41472), b256, 0, stream>>>(original, wsyx, out);
}